// Round 8
// baseline (262.295 us; speedup 1.0000x reference)
//
#include <hip/hip_runtime.h>

#define DD 64
#define NTE 512
#define SLOTMAX 64

using s8v   = __attribute__((ext_vector_type(8))) short;   // 8 bf16 (4 VGPRs)
using f32x4 = __attribute__((ext_vector_type(4))) float;   // MFMA C/D

typedef unsigned int   uint_t;
typedef unsigned short ushort_t;

union U8 { s8v v; uint_t u[4]; };

__device__ __forceinline__ float silu_f(float x) {
    return x / (1.0f + __expf(-x));
}
__device__ __forceinline__ float clamp100(float x) {
    return fminf(fmaxf(x, -100.0f), 100.0f);
}
__device__ __forceinline__ unsigned short f2bf(float x) {
    unsigned int u = __float_as_uint(x);
    return (unsigned short)((u + 0x7FFFu + ((u >> 16) & 1u)) >> 16);   // RNE
}
__device__ __forceinline__ uint_t cvt_pk_bf16(float lo, float hi) {
    uint_t r;
    asm("v_cvt_pk_bf16_f32 %0, %1, %2" : "=v"(r) : "v"(lo), "v"(hi));
    return r;
}

#define WAVE_FENCE() do { asm volatile("s_waitcnt lgkmcnt(0)" ::: "memory"); \
                          __builtin_amdgcn_sched_barrier(0); } while (0)

// ---------------------------------------------------------------------------
// Combined prep kernel. Sections by blockIdx:
//  [histBlocks): histogram + slot-assign, slots2[r][s] = {e, col(e)}
//  [hbfBlocks):  h (f32) -> bf16
//  [c4Blocks):   coord -> float4 [N,4]
//  [wfBlocks):   weight fragments:
//   mats 0..6, 4096 shorts each; mat7 @28672 (rank-3+be1); mat8 @30720 (be2,bc1)
//   mats 2/3 (We2/Wc1) use REMAPPED k = 16*(2*k0+(i>>2)) + 4*(lane>>4) + (i&3)
// ---------------------------------------------------------------------------
__global__ __launch_bounds__(256) void prep_all(
    const float* __restrict__ h,
    const float* __restrict__ coord,
    const float* __restrict__ We1, const float* __restrict__ We2,
    const float* __restrict__ Wc1,
    const float* __restrict__ Wn1, const float* __restrict__ Wn2,
    const float* __restrict__ be1, const float* __restrict__ be2,
    const float* __restrict__ bc1,
    const int*   __restrict__ ei,
    ushort_t* __restrict__ hbf,
    ushort_t* __restrict__ wf,
    float4* __restrict__ coord4,
    int* __restrict__ cnt_i,
    int2* __restrict__ slots2,
    int N, int E, int total8, int histBlocks, int hbfBlocks, int c4Blocks)
{
    const int b = blockIdx.x;
    if (b < histBlocks) {
        const int e = b * 256 + threadIdx.x;
        if (e < E) {
            const int r = ei[e];
            const int s = atomicAdd(&cnt_i[r], 1);
            if (s < SLOTMAX) {
                int2 v; v.x = e; v.y = ei[E + e];
                slots2[(size_t)r * SLOTMAX + s] = v;
            }
        }
    } else if (b < histBlocks + hbfBlocks) {
        const int t = (b - histBlocks) * 256 + threadIdx.x;
        if (t < total8) {
            const float4 v0 = ((const float4*)h)[t * 2 + 0];
            const float4 v1 = ((const float4*)h)[t * 2 + 1];
            uint4 o;
            o.x = (uint_t)f2bf(v0.x) | ((uint_t)f2bf(v0.y) << 16);
            o.y = (uint_t)f2bf(v0.z) | ((uint_t)f2bf(v0.w) << 16);
            o.z = (uint_t)f2bf(v1.x) | ((uint_t)f2bf(v1.y) << 16);
            o.w = (uint_t)f2bf(v1.z) | ((uint_t)f2bf(v1.w) << 16);
            ((uint4*)hbf)[t] = o;
        }
    } else if (b < histBlocks + hbfBlocks + c4Blocks) {
        const int t = (b - histBlocks - hbfBlocks) * 256 + threadIdx.x;
        if (t < N) {
            float4 c;
            c.x = coord[3 * t + 0];
            c.y = coord[3 * t + 1];
            c.z = coord[3 * t + 2];
            c.w = 0.0f;
            coord4[t] = c;
        }
    } else {
        const int t = (b - histBlocks - hbfBlocks - c4Blocks) * 256 + threadIdx.x;
        if (t >= 32768) return;
        if (t < 28672) {
            const int j    = t & 7;
            const int lane = (t >> 3) & 63;
            const int n0   = (t >> 9) & 3;
            const int k0   = (t >> 11) & 1;
            const int mat  = t >> 12;
            const int g    = lane >> 4;
            int k;
            if (mat == 2 || mat == 3) k = 16 * (2 * k0 + (j >> 2)) + 4 * g + (j & 3);
            else                      k = k0 * 32 + g * 8 + j;
            const int n = n0 * 16 + (lane & 15);
            float v;
            if      (mat == 0) v = We1[(size_t)k * 64 + n];
            else if (mat == 1) v = We1[(size_t)(64 + k) * 64 + n];
            else if (mat == 2) v = We2[(size_t)k * 64 + n];
            else if (mat == 3) v = Wc1[(size_t)k * 64 + n];
            else if (mat == 4) v = Wn1[(size_t)k * 64 + n];
            else if (mat == 5) v = Wn1[(size_t)(64 + k) * 64 + n];
            else               v = Wn2[(size_t)k * 64 + n];
            wf[t] = f2bf(v);
        } else {
            const int t2   = t - 28672;
            const int j    = t2 & 7;
            const int lane = (t2 >> 3) & 63;
            const int n0   = (t2 >> 9) & 3;
            const int xm   = (t2 >> 11) & 1;
            const int k = 8 * (lane >> 4) + j;
            const int m = n0 * 16 + (lane & 15);
            float v = 0.0f;
            if (xm == 0) {
                if      (k == 0) v = We1[(size_t)128 * 64 + m];
                else if (k == 1) v = We1[(size_t)129 * 64 + m];
                else if (k == 2) v = We1[(size_t)130 * 64 + m];
                else if (k == 3) v = be1[m];
            } else {
                if      (k == 0) v = be2[m];
                else if (k == 1) v = bc1[m];
            }
            wf[t] = f2bf(v);
        }
    }
}

// ---------------------------------------------------------------------------
// Edge kernel: one WAVE per NODE, 256-thread blocks (4 waves), weights-as-A /
// activations-as-B MFMA, in-register inter-layer chain.
// Round 8: whole-node slot broadcast (1 coalesced int2 load/node, per-tile
// distribution via shfl), one-tile-ahead gather prefetch (h frags + coord +
// ea), one-node-ahead prefetch (deg/slots/h[n]/coord[n]). launch_bounds
// (256,3): reg cap ~170 (no round-6 spills), residency 12 waves/CU.
// ---------------------------------------------------------------------------
__global__ __launch_bounds__(256, 3) void egcl_edge(
    const ushort_t* __restrict__ hbf,
    const ushort_t* __restrict__ wfG,
    const float4* __restrict__ coord4,
    const float* __restrict__ ea,
    const float* __restrict__ Wc2,
    const int* __restrict__ cnt_i,
    const int2* __restrict__ slots2,
    ushort_t* __restrict__ aggbf,    // [N,64] bf16 (sum of edge_feat)
    float* __restrict__ coord_out,   // [N,3]
    int N, int totalWaves)
{
    __shared__ ushort_t fragLDS[20480];   // mats 0..3 + mat7 + mat8 = 40 KB

    const int tid = threadIdx.x;
    #pragma unroll
    for (int i = 0; i < 8; ++i)
        ((uint4*)fragLDS)[tid + i * 256] = ((const uint4*)wfG)[tid + i * 256];
    ((uint4*)fragLDS)[2048 + tid]       = ((const uint4*)wfG)[3584 + tid];
    ((uint4*)fragLDS)[2048 + 256 + tid] = ((const uint4*)wfG)[3584 + 256 + tid];
    __syncthreads();

    const int wid  = tid >> 6;
    const int lane = tid & 63;
    const int l15  = lane & 15;
    const int g    = lane >> 4;

#define LD_W(mat, k0, m0) \
    (*(const s8v*)(fragLDS + ((((mat)*2 + (k0))*4 + (m0)) * 512) + lane * 8))
#define LD_X7(m0) (*(const s8v*)(fragLDS + 16384 + (m0) * 512 + lane * 8))
#define LD_XB(m0) (*(const s8v*)(fragLDS + 18432 + (m0) * 512 + lane * 8))

    float wc2_c[4][4];
    #pragma unroll
    for (int m0 = 0; m0 < 4; ++m0)
        #pragma unroll
        for (int j = 0; j < 4; ++j)
            wc2_c[m0][j] = Wc2[m0 * 16 + 4 * g + j];

    U8 b2f, bcf;   // constant bias-selector B fragments
    b2f.u[0] = 0x00003F80u; b2f.u[1] = 0; b2f.u[2] = 0; b2f.u[3] = 0;  // [1,0,..]
    bcf.u[0] = 0x3F800000u; bcf.u[1] = 0; bcf.u[2] = 0; bcf.u[3] = 0;  // [0,1,..]

    const f32x4 zero4 = {0.f, 0.f, 0.f, 0.f};

    int n = blockIdx.x * 4 + wid;

    // ---- one-node-ahead prefetch state ----
    int    pdeg = 0;
    int2   pslot; pslot.x = 0; pslot.y = 0;
    s8v    phn0{}, phn1{};
    float4 pcn4{};
    if (n < N) {
        pdeg  = cnt_i[n];
        pslot = slots2[(size_t)n * SLOTMAX + lane];   // lane = slot index
        const ushort_t* hn = hbf + (size_t)n * 64;
        phn0 = *(const s8v*)(hn + g * 8);
        phn1 = *(const s8v*)(hn + 32 + g * 8);
        pcn4 = coord4[n];
    }

    for (; n < N; n += totalWaves) {
        const int    deg    = pdeg;
        const int2   myslot = pslot;
        const s8v    bn0    = phn0;
        const s8v    bn1    = phn1;
        const float4 cn4    = pcn4;

        const int nn = n + totalWaves;
        if (nn < N) {                       // prefetch next node (independent)
            pdeg  = cnt_i[nn];
            pslot = slots2[(size_t)nn * SLOTMAX + lane];
            const ushort_t* hn2 = hbf + (size_t)nn * 64;
            phn0 = *(const s8v*)(hn2 + g * 8);
            phn1 = *(const s8v*)(hn2 + 32 + g * 8);
            pcn4 = coord4[nn];
        }

        const int effdeg = deg < SLOTMAX ? deg : SLOTMAX;
        const int ntile  = (effdeg + 15) >> 4;

        // ---- tile-0 gathers (addresses via in-wave shuffle of myslot) ----
        float4 c4c{}; float2 a2c{}; s8v bc0c{}, bc1c{};
        if (ntile > 0) {
            const int si = (l15 < effdeg) ? l15 : 0;
            const int ec = __shfl(myslot.x, si, 64);
            const int cc = __shfl(myslot.y, si, 64);
            c4c = coord4[cc];
            a2c = *(const float2*)(ea + 2 * (size_t)ec);
            const ushort_t* hc = hbf + (size_t)cc * 64;
            bc0c = *(const s8v*)(hc + g * 8);
            bc1c = *(const s8v*)(hc + 32 + g * 8);
        }

        // row-half of layer1 once per node (overlaps tile-0 gathers)
        f32x4 rowacc[4];
        #pragma unroll
        for (int m0 = 0; m0 < 4; ++m0) {
            f32x4 a = zero4;
            a = __builtin_amdgcn_mfma_f32_16x16x32_bf16(LD_W(0, 0, m0), bn0, a, 0, 0, 0);
            a = __builtin_amdgcn_mfma_f32_16x16x32_bf16(LD_W(0, 1, m0), bn1, a, 0, 0, 0);
            rowacc[m0] = a;
        }

        float hsum[4][4];
        #pragma unroll
        for (int m0 = 0; m0 < 4; ++m0)
            #pragma unroll
            for (int j = 0; j < 4; ++j) hsum[m0][j] = 0.f;
        float txs = 0.f, tys = 0.f, tzs = 0.f;

        for (int t = 0; t < ntile; ++t) {
            const int s = t * 16 + l15;
            const bool val = (s < effdeg);
            const float valf = val ? 1.0f : 0.0f;

            // ---- prefetch tile t+1 gathers (overlap full tile compute) ----
            float4 c4n{}; float2 a2n{}; s8v bc0n{}, bc1n{};
            {
                const int s2 = s + 16;
                const int si = (s2 < effdeg) ? s2 : 0;
                const int en = __shfl(myslot.x, si, 64);
                const int cn = __shfl(myslot.y, si, 64);
                if (t + 1 < ntile) {
                    c4n = coord4[cn];
                    a2n = *(const float2*)(ea + 2 * (size_t)en);
                    const ushort_t* hc2 = hbf + (size_t)cn * 64;
                    bc0n = *(const s8v*)(hc2 + g * 8);
                    bc1n = *(const s8v*)(hc2 + 32 + g * 8);
                }
            }

            const float dx = cn4.x - c4c.x, dy = cn4.y - c4c.y, dz = cn4.z - c4c.z;
            const float radial = dx * dx + dy * dy + dz * dz;

            U8 ex;   // extra k-block input: [radial, ea0, ea1, 1]
            ex.u[0] = cvt_pk_bf16(radial, a2c.x);
            ex.u[1] = cvt_pk_bf16(a2c.y, 1.0f);
            ex.u[2] = 0; ex.u[3] = 0;

            // ---- layer 1 ----
            f32x4 c1[4];
            #pragma unroll
            for (int m0 = 0; m0 < 4; ++m0) {
                f32x4 a = rowacc[m0];
                a = __builtin_amdgcn_mfma_f32_16x16x32_bf16(LD_W(1, 0, m0), bc0c, a, 0, 0, 0);
                a = __builtin_amdgcn_mfma_f32_16x16x32_bf16(LD_W(1, 1, m0), bc1c, a, 0, 0, 0);
                a = __builtin_amdgcn_mfma_f32_16x16x32_bf16(LD_X7(m0),      ex.v, a, 0, 0, 0);
                c1[m0] = a;
            }

            // silu + in-register repack to next layer's B fragment
            U8 f2a, f2b;
            #pragma unroll
            for (int m0 = 0; m0 < 4; ++m0) {
                const float ya = silu_f(c1[m0][0]);
                const float yb = silu_f(c1[m0][1]);
                const float yc = silu_f(c1[m0][2]);
                const float yd = silu_f(c1[m0][3]);
                U8& dst = (m0 < 2) ? f2a : f2b;
                dst.u[(m0 & 1) * 2 + 0] = cvt_pk_bf16(ya, yb);
                dst.u[(m0 & 1) * 2 + 1] = cvt_pk_bf16(yc, yd);
            }

            // ---- layer 2 (edge_feat) ----
            f32x4 c2[4];
            #pragma unroll
            for (int m0 = 0; m0 < 4; ++m0) {
                f32x4 a = zero4;
                a = __builtin_amdgcn_mfma_f32_16x16x32_bf16(LD_W(2, 0, m0), f2a.v, a, 0, 0, 0);
                a = __builtin_amdgcn_mfma_f32_16x16x32_bf16(LD_W(2, 1, m0), f2b.v, a, 0, 0, 0);
                a = __builtin_amdgcn_mfma_f32_16x16x32_bf16(LD_XB(m0),      b2f.v, a, 0, 0, 0);
                c2[m0] = a;
            }

            U8 f3a, f3b;
            #pragma unroll
            for (int m0 = 0; m0 < 4; ++m0) {
                const float ya = silu_f(c2[m0][0]);
                const float yb = silu_f(c2[m0][1]);
                const float yc = silu_f(c2[m0][2]);
                const float yd = silu_f(c2[m0][3]);
                hsum[m0][0] = fmaf(ya, valf, hsum[m0][0]);
                hsum[m0][1] = fmaf(yb, valf, hsum[m0][1]);
                hsum[m0][2] = fmaf(yc, valf, hsum[m0][2]);
                hsum[m0][3] = fmaf(yd, valf, hsum[m0][3]);
                U8& dst = (m0 < 2) ? f3a : f3b;
                dst.u[(m0 & 1) * 2 + 0] = cvt_pk_bf16(ya, yb);
                dst.u[(m0 & 1) * 2 + 1] = cvt_pk_bf16(yc, yd);
            }

            // ---- coord head: 64 -> 64 -> 1 ----
            float p = 0.f;
            #pragma unroll
            for (int m0 = 0; m0 < 4; ++m0) {
                f32x4 a = zero4;
                a = __builtin_amdgcn_mfma_f32_16x16x32_bf16(LD_W(3, 0, m0), f3a.v, a, 0, 0, 0);
                a = __builtin_amdgcn_mfma_f32_16x16x32_bf16(LD_W(3, 1, m0), f3b.v, a, 0, 0, 0);
                a = __builtin_amdgcn_mfma_f32_16x16x32_bf16(LD_XB(m0),      bcf.v, a, 0, 0, 0);
                #pragma unroll
                for (int j = 0; j < 4; ++j)
                    p = fmaf(silu_f(a[j]), wc2_c[m0][j], p);
            }
            p += __shfl_xor(p, 16, 64);
            p += __shfl_xor(p, 32, 64);
            const float sc = p * valf;
            txs += clamp100(dx * sc);   // 4x redundant across g; /4 folded below
            tys += clamp100(dy * sc);
            tzs += clamp100(dz * sc);

            // ---- rotate pipeline ----
            if (t + 1 < ntile) {
                c4c = c4n; a2c = a2n; bc0c = bc0n; bc1c = bc1n;
            }
        }

        // ---- node epilogue ----
        #pragma unroll
        for (int m0 = 0; m0 < 4; ++m0) {
            #pragma unroll
            for (int j = 0; j < 4; ++j) {
                float v = hsum[m0][j];
                v += __shfl_xor(v, 1, 64);
                v += __shfl_xor(v, 2, 64);
                v += __shfl_xor(v, 4, 64);
                v += __shfl_xor(v, 8, 64);
                hsum[m0][j] = v;
            }
        }
        if (l15 == 0) {
            uint_t* ab = (uint_t*)aggbf + (size_t)n * 32 + 2 * g;
            #pragma unroll
            for (int m0 = 0; m0 < 4; ++m0) {
                ab[8 * m0 + 0] = cvt_pk_bf16(hsum[m0][0], hsum[m0][1]);
                ab[8 * m0 + 1] = cvt_pk_bf16(hsum[m0][2], hsum[m0][3]);
            }
        }
        #pragma unroll
        for (int msk = 1; msk < 64; msk <<= 1) {
            txs += __shfl_xor(txs, msk, 64);
            tys += __shfl_xor(tys, msk, 64);
            tzs += __shfl_xor(tzs, msk, 64);
        }
        if (lane == 0) {
            const float inv = 0.25f / fmaxf((float)deg, 1.0f);
            coord_out[(size_t)n * 3 + 0] = cn4.x + txs * inv;
            coord_out[(size_t)n * 3 + 1] = cn4.y + tys * inv;
            coord_out[(size_t)n * 3 + 2] = cn4.z + tzs * inv;
        }
    }
#undef LD_W
#undef LD_X7
#undef LD_XB
}

// ---------------------------------------------------------------------------
// Node kernel: one wave per 16 nodes, MFMA over [h||agg] (K=128) -> 64 -> 64.
// ---------------------------------------------------------------------------
__global__ __launch_bounds__(NTE, 4) void egcl_node(
    const ushort_t* __restrict__ hbf,
    const ushort_t* __restrict__ aggbf,
    const ushort_t* __restrict__ wfG,   // node mats at +16384
    const float* __restrict__ h,
    const float* __restrict__ bn1,
    const float* __restrict__ bn2,
    float* __restrict__ h_out,
    int N)
{
    __shared__ ushort_t fragLDS[12288];      // mats 4..6, 24 KB
    __shared__ ushort_t ldsY[8][16 * 72];

    const int tid = threadIdx.x;
    #pragma unroll
    for (int i = 0; i < 3; ++i)
        ((uint4*)fragLDS)[tid + i * 512] = ((const uint4*)(wfG + 16384))[tid + i * 512];
    __syncthreads();

    const int wid  = tid >> 6;
    const int lane = tid & 63;
    const int l15  = lane & 15;
    const int g    = lane >> 4;

#define LD_WN(mat, k0, n0) \
    (*(const s8v*)(fragLDS + ((((mat)*2 + (k0))*4 + (n0)) * 512) + lane * 8))

    float bn1_c[4], bn2_c[4];
    #pragma unroll
    for (int n0 = 0; n0 < 4; ++n0) {
        bn1_c[n0] = bn1[n0 * 16 + l15];
        bn2_c[n0] = bn2[n0 * 16 + l15];
    }

    const int wg = blockIdx.x * 8 + wid;
    const int nb = wg * 16;
    if (nb >= N) return;

    const int nod  = nb + l15;
    const int nodL = nod < N ? nod : N - 1;
    const ushort_t* hrow = hbf   + (size_t)nodL * 64;
    const ushort_t* arow = aggbf + (size_t)nodL * 64;
    const s8v aH0 = *(const s8v*)(hrow + g * 8);
    const s8v aH1 = *(const s8v*)(hrow + 32 + g * 8);
    const s8v aG0 = *(const s8v*)(arow + g * 8);
    const s8v aG1 = *(const s8v*)(arow + 32 + g * 8);

    ushort_t* yw = ldsY[wid];
    #pragma unroll
    for (int n0 = 0; n0 < 4; ++n0) {
        f32x4 a = {0.f, 0.f, 0.f, 0.f};
        a = __builtin_amdgcn_mfma_f32_16x16x32_bf16(aH0, LD_WN(0, 0, n0), a, 0, 0, 0);
        a = __builtin_amdgcn_mfma_f32_16x16x32_bf16(aH1, LD_WN(0, 1, n0), a, 0, 0, 0);
        a = __builtin_amdgcn_mfma_f32_16x16x32_bf16(aG0, LD_WN(1, 0, n0), a, 0, 0, 0);
        a = __builtin_amdgcn_mfma_f32_16x16x32_bf16(aG1, LD_WN(1, 1, n0), a, 0, 0, 0);
        #pragma unroll
        for (int jj = 0; jj < 4; ++jj)
            yw[(g * 4 + jj) * 72 + n0 * 16 + l15] = f2bf(silu_f(a[jj] + bn1_c[n0]));
    }
    WAVE_FENCE();

    const ushort_t* yrow = yw + l15 * 72;
    const s8v b0 = *(const s8v*)(yrow + g * 8);
    const s8v b1 = *(const s8v*)(yrow + 32 + g * 8);
    #pragma unroll
    for (int n0 = 0; n0 < 4; ++n0) {
        f32x4 a = {0.f, 0.f, 0.f, 0.f};
        a = __builtin_amdgcn_mfma_f32_16x16x32_bf16(b0, LD_WN(2, 0, n0), a, 0, 0, 0);
        a = __builtin_amdgcn_mfma_f32_16x16x32_bf16(b1, LD_WN(2, 1, n0), a, 0, 0, 0);
        #pragma unroll
        for (int jj = 0; jj < 4; ++jj) {
            const int m = nb + g * 4 + jj;
            if (m < N) {
                const size_t idx = (size_t)m * 64 + n0 * 16 + l15;
                h_out[idx] = h[idx] + (a[jj] + bn2_c[n0]);
            }
        }
    }
#undef LD_WN
}

extern "C" void kernel_launch(void* const* d_in, const int* in_sizes, int n_in,
                              void* d_out, int out_size, void* d_ws, size_t ws_size,
                              hipStream_t stream) {
    const float* h     = (const float*)d_in[0];
    const float* coord = (const float*)d_in[1];
    const int*   ei    = (const int*)  d_in[2];
    const float* ea    = (const float*)d_in[3];
    const float* We1   = (const float*)d_in[4];
    const float* be1   = (const float*)d_in[5];
    const float* We2   = (const float*)d_in[6];
    const float* be2   = (const float*)d_in[7];
    const float* Wn1   = (const float*)d_in[8];
    const float* bn1   = (const float*)d_in[9];
    const float* Wn2   = (const float*)d_in[10];
    const float* bn2   = (const float*)d_in[11];
    const float* Wc1   = (const float*)d_in[12];
    const float* bc1   = (const float*)d_in[13];
    const float* Wc2   = (const float*)d_in[14];

    const int N = in_sizes[0] / DD;     // h is [N,64]
    const int E = in_sizes[3] / 2;      // edge_attr is [E,2]

    float* out       = (float*)d_out;
    float* h_out     = out;
    float* coord_out = out + (size_t)N * DD;

    // workspace layout (16B aligned)
    char* base = (char*)d_ws;
    ushort_t* hbf   = (ushort_t*)base;                              // N*64*2 B
    const size_t o_wf    = (size_t)N * DD * 2;
    ushort_t* wf    = (ushort_t*)(base + o_wf);                     // 32768*2 B
    const size_t o_agg   = o_wf + 32768 * 2;
    ushort_t* aggbf = (ushort_t*)(base + o_agg);                    // N*64*2 B
    const size_t o_c4    = o_agg + (size_t)N * DD * 2;
    float4* coord4  = (float4*)(base + o_c4);                       // N*16 B
    const size_t o_cnt   = o_c4 + (size_t)N * 16;
    int* cnt_i      = (int*)(base + o_cnt);                         // N*4 B
    const size_t o_slots = o_cnt + (size_t)N * 4;
    int2* slots2    = (int2*)(base + o_slots);                      // N*SLOTMAX*8 B

    hipMemsetAsync((void*)cnt_i, 0, (size_t)N * 4, stream);

    // combined prep: hist+slots | h->bf16 | coord4 | weight frags
    const int histBlocks = (E + 255) / 256;
    const int total8     = N * DD / 8;
    const int hbfBlocks  = (total8 + 255) / 256;
    const int c4Blocks   = (N + 255) / 256;
    const int wfBlocks   = (32768 + 255) / 256;
    prep_all<<<histBlocks + hbfBlocks + c4Blocks + wfBlocks, 256, 0, stream>>>(
        h, coord, We1, We2, Wc1, Wn1, Wn2, be1, be2, bc1, ei,
        hbf, wf, coord4, cnt_i, slots2, N, E, total8,
        histBlocks, hbfBlocks, c4Blocks);

    // edge: persistent, one wave per node; 2048 blocks x 4 waves
    const int eblocks = 2048;
    const int totalWaves = eblocks * 4;
    egcl_edge<<<eblocks, 256, 0, stream>>>(
        hbf, wf, coord4, ea, Wc2,
        cnt_i, slots2, aggbf, coord_out, N, totalWaves);

    // node: one wave per 16 nodes
    const int nwaves  = (N + 15) / 16;
    const int nblocks = (nwaves + 7) / 8;
    egcl_node<<<nblocks, NTE, 0, stream>>>(
        hbf, aggbf, wf, h, bn1, bn2, h_out, N);
}

// Round 9
// 216.844 us; speedup vs baseline: 1.2096x; 1.2096x over previous
//
#include <hip/hip_runtime.h>

#define DD 64
#define SLOTMAX 64

using s8v   = __attribute__((ext_vector_type(8))) short;   // 8 bf16 (4 VGPRs)
using f32x4 = __attribute__((ext_vector_type(4))) float;   // MFMA C/D

typedef unsigned int   uint_t;
typedef unsigned short ushort_t;

union U8 { s8v v; uint_t u[4]; };

__device__ __forceinline__ float silu_f(float x) {
    return x / (1.0f + __expf(-x));
}
__device__ __forceinline__ float clamp100(float x) {
    return fminf(fmaxf(x, -100.0f), 100.0f);
}
__device__ __forceinline__ unsigned short f2bf(float x) {
    unsigned int u = __float_as_uint(x);
    return (unsigned short)((u + 0x7FFFu + ((u >> 16) & 1u)) >> 16);   // RNE
}
__device__ __forceinline__ float bf2f(ushort_t v) {
    return __uint_as_float(((uint_t)v) << 16);
}
__device__ __forceinline__ uint_t cvt_pk_bf16(float lo, float hi) {
    uint_t r;
    asm("v_cvt_pk_bf16_f32 %0, %1, %2" : "=v"(r) : "v"(lo), "v"(hi));
    return r;
}

#define WAVE_FENCE() do { asm volatile("s_waitcnt lgkmcnt(0)" ::: "memory"); \
                          __builtin_amdgcn_sched_barrier(0); } while (0)

// ---------------------------------------------------------------------------
// Combined prep kernel. Sections by blockIdx:
//  [histBlocks): histogram + slot-assign, slots[r][s] = e   (int)
//  [hbfBlocks):  h (f32) -> bf16
//  [c4Blocks):   coord -> float4 [N,4]
//  [wfBlocks):   weight fragments:
//   mats 0..6, 4096 shorts each; mat7 @28672 (rank-3+be1); mat8 @30720 (be2,bc1)
//   mats 2/3 (We2/Wc1) use REMAPPED k = 16*(2*k0+(i>>2)) + 4*(lane>>4) + (i&3)
// ---------------------------------------------------------------------------
__global__ __launch_bounds__(256) void prep_all(
    const float* __restrict__ h,
    const float* __restrict__ coord,
    const float* __restrict__ We1, const float* __restrict__ We2,
    const float* __restrict__ Wc1,
    const float* __restrict__ Wn1, const float* __restrict__ Wn2,
    const float* __restrict__ be1, const float* __restrict__ be2,
    const float* __restrict__ bc1,
    const int*   __restrict__ ei,
    ushort_t* __restrict__ hbf,
    ushort_t* __restrict__ wf,
    float4* __restrict__ coord4,
    int* __restrict__ cnt_i,
    int* __restrict__ slots,
    int N, int E, int total8, int histBlocks, int hbfBlocks, int c4Blocks)
{
    const int b = blockIdx.x;
    if (b < histBlocks) {
        const int e = b * 256 + threadIdx.x;
        if (e < E) {
            const int r = ei[e];
            const int s = atomicAdd(&cnt_i[r], 1);
            if (s < SLOTMAX) slots[(size_t)r * SLOTMAX + s] = e;
        }
    } else if (b < histBlocks + hbfBlocks) {
        const int t = (b - histBlocks) * 256 + threadIdx.x;
        if (t < total8) {
            const float4 v0 = ((const float4*)h)[t * 2 + 0];
            const float4 v1 = ((const float4*)h)[t * 2 + 1];
            uint4 o;
            o.x = (uint_t)f2bf(v0.x) | ((uint_t)f2bf(v0.y) << 16);
            o.y = (uint_t)f2bf(v0.z) | ((uint_t)f2bf(v0.w) << 16);
            o.z = (uint_t)f2bf(v1.x) | ((uint_t)f2bf(v1.y) << 16);
            o.w = (uint_t)f2bf(v1.z) | ((uint_t)f2bf(v1.w) << 16);
            ((uint4*)hbf)[t] = o;
        }
    } else if (b < histBlocks + hbfBlocks + c4Blocks) {
        const int t = (b - histBlocks - hbfBlocks) * 256 + threadIdx.x;
        if (t < N) {
            float4 c;
            c.x = coord[3 * t + 0];
            c.y = coord[3 * t + 1];
            c.z = coord[3 * t + 2];
            c.w = 0.0f;
            coord4[t] = c;
        }
    } else {
        const int t = (b - histBlocks - hbfBlocks - c4Blocks) * 256 + threadIdx.x;
        if (t >= 32768) return;
        if (t < 28672) {
            const int j    = t & 7;
            const int lane = (t >> 3) & 63;
            const int n0   = (t >> 9) & 3;
            const int k0   = (t >> 11) & 1;
            const int mat  = t >> 12;
            const int g    = lane >> 4;
            int k;
            if (mat == 2 || mat == 3) k = 16 * (2 * k0 + (j >> 2)) + 4 * g + (j & 3);
            else                      k = k0 * 32 + g * 8 + j;
            const int n = n0 * 16 + (lane & 15);
            float v;
            if      (mat == 0) v = We1[(size_t)k * 64 + n];
            else if (mat == 1) v = We1[(size_t)(64 + k) * 64 + n];
            else if (mat == 2) v = We2[(size_t)k * 64 + n];
            else if (mat == 3) v = Wc1[(size_t)k * 64 + n];
            else if (mat == 4) v = Wn1[(size_t)k * 64 + n];
            else if (mat == 5) v = Wn1[(size_t)(64 + k) * 64 + n];
            else               v = Wn2[(size_t)k * 64 + n];
            wf[t] = f2bf(v);
        } else {
            const int t2   = t - 28672;
            const int j    = t2 & 7;
            const int lane = (t2 >> 3) & 63;
            const int n0   = (t2 >> 9) & 3;
            const int xm   = (t2 >> 11) & 1;
            const int k = 8 * (lane >> 4) + j;
            const int m = n0 * 16 + (lane & 15);
            float v = 0.0f;
            if (xm == 0) {
                if      (k == 0) v = We1[(size_t)128 * 64 + m];
                else if (k == 1) v = We1[(size_t)129 * 64 + m];
                else if (k == 2) v = We1[(size_t)130 * 64 + m];
                else if (k == 3) v = be1[m];
            } else {
                if      (k == 0) v = be2[m];
                else if (k == 1) v = bc1[m];
            }
            wf[t] = f2bf(v);
        }
    }
}

// ---------------------------------------------------------------------------
// Edge kernel, EDGE-MAJOR: one wave per 16 CONSECUTIVE edges (zero padding,
// no slot table, no atomics, no per-node state). layer1 = h[row]@W1a +
// h[col]@W1b + rank3 (5 MFMAs per m0). Writes edge_feat (bf16, coalesced
// uint2 stores) and trans4 (f32x4: clamped trans + 1.0 count).
// ---------------------------------------------------------------------------
__global__ __launch_bounds__(512, 4) void egcl_edge(
    const ushort_t* __restrict__ hbf,
    const ushort_t* __restrict__ wfG,
    const float4* __restrict__ coord4,
    const int*   __restrict__ ei,
    const float* __restrict__ ea,
    const float* __restrict__ Wc2,
    uint_t* __restrict__ efu,        // edge_feat as u32 pairs [E][32]
    float4* __restrict__ trans4,     // [E]
    int E, int ntiles, int totalWaves)
{
    __shared__ ushort_t fragLDS[20480];   // mats 0..3 + mat7 + mat8 = 40 KB

    const int tid = threadIdx.x;
    #pragma unroll
    for (int i = 0; i < 4; ++i)
        ((uint4*)fragLDS)[tid + i * 512] = ((const uint4*)wfG)[tid + i * 512];
    ((uint4*)fragLDS)[2048 + tid] = ((const uint4*)wfG)[3584 + tid];
    __syncthreads();

    const int wid  = tid >> 6;
    const int lane = tid & 63;
    const int l15  = lane & 15;
    const int g    = lane >> 4;

#define LD_W(mat, k0, m0) \
    (*(const s8v*)(fragLDS + ((((mat)*2 + (k0))*4 + (m0)) * 512) + lane * 8))
#define LD_X7(m0) (*(const s8v*)(fragLDS + 16384 + (m0) * 512 + lane * 8))
#define LD_XB(m0) (*(const s8v*)(fragLDS + 18432 + (m0) * 512 + lane * 8))

    float wc2_c[4][4];
    #pragma unroll
    for (int m0 = 0; m0 < 4; ++m0)
        #pragma unroll
        for (int j = 0; j < 4; ++j)
            wc2_c[m0][j] = Wc2[m0 * 16 + 4 * g + j];

    U8 b2f, bcf;   // constant bias-selector B fragments
    b2f.u[0] = 0x00003F80u; b2f.u[1] = 0; b2f.u[2] = 0; b2f.u[3] = 0;  // [1,0,..]
    bcf.u[0] = 0x3F800000u; bcf.u[1] = 0; bcf.u[2] = 0; bcf.u[3] = 0;  // [0,1,..]

    const f32x4 zero4 = {0.f, 0.f, 0.f, 0.f};

    for (int t = blockIdx.x * 8 + wid; t < ntiles; t += totalWaves) {
        const int e   = t * 16 + l15;
        const bool val = (e < E);
        const int eL  = val ? e : (E - 1);

        const int row = ei[eL];
        const int col = ei[E + eL];
        const float4 cr = coord4[row];
        const float4 cc = coord4[col];
        const float2 a2 = *(const float2*)(ea + 2 * (size_t)eL);
        const ushort_t* hr = hbf + (size_t)row * 64;
        const ushort_t* hc = hbf + (size_t)col * 64;
        const s8v br0 = *(const s8v*)(hr + g * 8);
        const s8v br1 = *(const s8v*)(hr + 32 + g * 8);
        const s8v bc0 = *(const s8v*)(hc + g * 8);
        const s8v bc1 = *(const s8v*)(hc + 32 + g * 8);

        const float dx = cr.x - cc.x, dy = cr.y - cc.y, dz = cr.z - cc.z;
        const float radial = dx * dx + dy * dy + dz * dz;

        U8 ex;   // extra k-block input: [radial, ea0, ea1, 1]
        ex.u[0] = cvt_pk_bf16(radial, a2.x);
        ex.u[1] = cvt_pk_bf16(a2.y, 1.0f);
        ex.u[2] = 0; ex.u[3] = 0;

        // ---- layer 1: row-half + col-half + rank3 ----
        f32x4 c1[4];
        #pragma unroll
        for (int m0 = 0; m0 < 4; ++m0) {
            f32x4 a = zero4;
            a = __builtin_amdgcn_mfma_f32_16x16x32_bf16(LD_W(0, 0, m0), br0, a, 0, 0, 0);
            a = __builtin_amdgcn_mfma_f32_16x16x32_bf16(LD_W(0, 1, m0), br1, a, 0, 0, 0);
            a = __builtin_amdgcn_mfma_f32_16x16x32_bf16(LD_W(1, 0, m0), bc0, a, 0, 0, 0);
            a = __builtin_amdgcn_mfma_f32_16x16x32_bf16(LD_W(1, 1, m0), bc1, a, 0, 0, 0);
            a = __builtin_amdgcn_mfma_f32_16x16x32_bf16(LD_X7(m0),      ex.v, a, 0, 0, 0);
            c1[m0] = a;
        }

        // silu + in-register repack to next layer's B fragment
        U8 f2a, f2b;
        #pragma unroll
        for (int m0 = 0; m0 < 4; ++m0) {
            const float ya = silu_f(c1[m0][0]);
            const float yb = silu_f(c1[m0][1]);
            const float yc = silu_f(c1[m0][2]);
            const float yd = silu_f(c1[m0][3]);
            U8& dst = (m0 < 2) ? f2a : f2b;
            dst.u[(m0 & 1) * 2 + 0] = cvt_pk_bf16(ya, yb);
            dst.u[(m0 & 1) * 2 + 1] = cvt_pk_bf16(yc, yd);
        }

        // ---- layer 2 (edge_feat) ----
        f32x4 c2[4];
        #pragma unroll
        for (int m0 = 0; m0 < 4; ++m0) {
            f32x4 a = zero4;
            a = __builtin_amdgcn_mfma_f32_16x16x32_bf16(LD_W(2, 0, m0), f2a.v, a, 0, 0, 0);
            a = __builtin_amdgcn_mfma_f32_16x16x32_bf16(LD_W(2, 1, m0), f2b.v, a, 0, 0, 0);
            a = __builtin_amdgcn_mfma_f32_16x16x32_bf16(LD_XB(m0),      b2f.v, a, 0, 0, 0);
            c2[m0] = a;
        }

        // silu, store edge_feat, build coord-head fragments
        uint_t* efrow = efu + (size_t)e * 32;
        U8 f3a, f3b;
        #pragma unroll
        for (int m0 = 0; m0 < 4; ++m0) {
            const float ya = silu_f(c2[m0][0]);
            const float yb = silu_f(c2[m0][1]);
            const float yc = silu_f(c2[m0][2]);
            const float yd = silu_f(c2[m0][3]);
            const uint_t p0 = cvt_pk_bf16(ya, yb);
            const uint_t p1 = cvt_pk_bf16(yc, yd);
            U8& dst = (m0 < 2) ? f3a : f3b;
            dst.u[(m0 & 1) * 2 + 0] = p0;
            dst.u[(m0 & 1) * 2 + 1] = p1;
            if (val) {
                uint2 st; st.x = p0; st.y = p1;
                *(uint2*)(efrow + m0 * 8 + g * 2) = st;   // dims 16m0+4g..+3
            }
        }

        // ---- coord head: 64 -> 64 -> 1 ----
        float p = 0.f;
        #pragma unroll
        for (int m0 = 0; m0 < 4; ++m0) {
            f32x4 a = zero4;
            a = __builtin_amdgcn_mfma_f32_16x16x32_bf16(LD_W(3, 0, m0), f3a.v, a, 0, 0, 0);
            a = __builtin_amdgcn_mfma_f32_16x16x32_bf16(LD_W(3, 1, m0), f3b.v, a, 0, 0, 0);
            a = __builtin_amdgcn_mfma_f32_16x16x32_bf16(LD_XB(m0),      bcf.v, a, 0, 0, 0);
            #pragma unroll
            for (int j = 0; j < 4; ++j)
                p = fmaf(silu_f(a[j]), wc2_c[m0][j], p);
        }
        p += __shfl_xor(p, 16, 64);   // reduce over the 4 g-lanes (dims)
        p += __shfl_xor(p, 32, 64);

        if (val && g == 0) {
            float4 tr;
            tr.x = clamp100(dx * p);
            tr.y = clamp100(dy * p);
            tr.z = clamp100(dz * p);
            tr.w = 1.0f;
            trans4[e] = tr;
        }
    }
#undef LD_W
#undef LD_X7
#undef LD_XB
}

// ---------------------------------------------------------------------------
// Aggregation kernel: one WAVE per node (lane = dim). Gathers the node's
// edge_feat rows (128B coalesced each) via the slot list, sums in fp32,
// also sums trans4; writes aggbf + coord_out. Pure memory kernel.
// ---------------------------------------------------------------------------
__global__ __launch_bounds__(256) void egcl_agg(
    const ushort_t* __restrict__ efbf,
    const float4* __restrict__ trans4,
    const int* __restrict__ slots,
    const int* __restrict__ cnt_i,
    const float4* __restrict__ coord4,
    ushort_t* __restrict__ aggbf,
    float* __restrict__ coord_out,
    int N)
{
    const int wid  = threadIdx.x >> 6;
    const int lane = threadIdx.x & 63;
    const int n = blockIdx.x * 4 + wid;
    if (n >= N) return;

    const int deg = cnt_i[n];
    const int eff = deg < SLOTMAX ? deg : SLOTMAX;
    const int* sp = slots + (size_t)n * SLOTMAX;

    float a0 = 0.f, a1 = 0.f, a2 = 0.f, a3 = 0.f;
    float tx = 0.f, ty = 0.f, tz = 0.f;

    int s = 0;
    for (; s + 4 <= eff; s += 4) {
        const int e0 = sp[s], e1 = sp[s + 1], e2 = sp[s + 2], e3 = sp[s + 3];
        const float4 t0 = trans4[e0], t1 = trans4[e1], t2 = trans4[e2], t3 = trans4[e3];
        const ushort_t v0 = efbf[(size_t)e0 * 64 + lane];
        const ushort_t v1 = efbf[(size_t)e1 * 64 + lane];
        const ushort_t v2 = efbf[(size_t)e2 * 64 + lane];
        const ushort_t v3 = efbf[(size_t)e3 * 64 + lane];
        a0 += bf2f(v0); a1 += bf2f(v1); a2 += bf2f(v2); a3 += bf2f(v3);
        tx += t0.x + t1.x + t2.x + t3.x;
        ty += t0.y + t1.y + t2.y + t3.y;
        tz += t0.z + t1.z + t2.z + t3.z;
    }
    for (; s < eff; ++s) {
        const int e0 = sp[s];
        a0 += bf2f(efbf[(size_t)e0 * 64 + lane]);
        const float4 t0 = trans4[e0];
        tx += t0.x; ty += t0.y; tz += t0.z;
    }

    aggbf[(size_t)n * 64 + lane] = f2bf(a0 + a1 + a2 + a3);
    if (lane == 0) {
        const float inv = 1.0f / fmaxf((float)deg, 1.0f);
        const float4 cn = coord4[n];
        coord_out[(size_t)n * 3 + 0] = cn.x + tx * inv;
        coord_out[(size_t)n * 3 + 1] = cn.y + ty * inv;
        coord_out[(size_t)n * 3 + 2] = cn.z + tz * inv;
    }
}

// ---------------------------------------------------------------------------
// Node kernel: one wave per 16 nodes, MFMA over [h||agg] (K=128) -> 64 -> 64.
// ---------------------------------------------------------------------------
__global__ __launch_bounds__(512, 4) void egcl_node(
    const ushort_t* __restrict__ hbf,
    const ushort_t* __restrict__ aggbf,
    const ushort_t* __restrict__ wfG,   // node mats at +16384
    const float* __restrict__ h,
    const float* __restrict__ bn1,
    const float* __restrict__ bn2,
    float* __restrict__ h_out,
    int N)
{
    __shared__ ushort_t fragLDS[12288];      // mats 4..6, 24 KB
    __shared__ ushort_t ldsY[8][16 * 72];

    const int tid = threadIdx.x;
    #pragma unroll
    for (int i = 0; i < 3; ++i)
        ((uint4*)fragLDS)[tid + i * 512] = ((const uint4*)(wfG + 16384))[tid + i * 512];
    __syncthreads();

    const int wid  = tid >> 6;
    const int lane = tid & 63;
    const int l15  = lane & 15;
    const int g    = lane >> 4;

#define LD_WN(mat, k0, n0) \
    (*(const s8v*)(fragLDS + ((((mat)*2 + (k0))*4 + (n0)) * 512) + lane * 8))

    float bn1_c[4], bn2_c[4];
    #pragma unroll
    for (int n0 = 0; n0 < 4; ++n0) {
        bn1_c[n0] = bn1[n0 * 16 + l15];
        bn2_c[n0] = bn2[n0 * 16 + l15];
    }

    const int wg = blockIdx.x * 8 + wid;
    const int nb = wg * 16;
    if (nb >= N) return;

    const int nod  = nb + l15;
    const int nodL = nod < N ? nod : N - 1;
    const ushort_t* hrow = hbf   + (size_t)nodL * 64;
    const ushort_t* arow = aggbf + (size_t)nodL * 64;
    const s8v aH0 = *(const s8v*)(hrow + g * 8);
    const s8v aH1 = *(const s8v*)(hrow + 32 + g * 8);
    const s8v aG0 = *(const s8v*)(arow + g * 8);
    const s8v aG1 = *(const s8v*)(arow + 32 + g * 8);

    ushort_t* yw = ldsY[wid];
    #pragma unroll
    for (int n0 = 0; n0 < 4; ++n0) {
        f32x4 a = {0.f, 0.f, 0.f, 0.f};
        a = __builtin_amdgcn_mfma_f32_16x16x32_bf16(aH0, LD_WN(0, 0, n0), a, 0, 0, 0);
        a = __builtin_amdgcn_mfma_f32_16x16x32_bf16(aH1, LD_WN(0, 1, n0), a, 0, 0, 0);
        a = __builtin_amdgcn_mfma_f32_16x16x32_bf16(aG0, LD_WN(1, 0, n0), a, 0, 0, 0);
        a = __builtin_amdgcn_mfma_f32_16x16x32_bf16(aG1, LD_WN(1, 1, n0), a, 0, 0, 0);
        #pragma unroll
        for (int jj = 0; jj < 4; ++jj)
            yw[(g * 4 + jj) * 72 + n0 * 16 + l15] = f2bf(silu_f(a[jj] + bn1_c[n0]));
    }
    WAVE_FENCE();

    const ushort_t* yrow = yw + l15 * 72;
    const s8v b0 = *(const s8v*)(yrow + g * 8);
    const s8v b1 = *(const s8v*)(yrow + 32 + g * 8);
    #pragma unroll
    for (int n0 = 0; n0 < 4; ++n0) {
        f32x4 a = {0.f, 0.f, 0.f, 0.f};
        a = __builtin_amdgcn_mfma_f32_16x16x32_bf16(b0, LD_WN(2, 0, n0), a, 0, 0, 0);
        a = __builtin_amdgcn_mfma_f32_16x16x32_bf16(b1, LD_WN(2, 1, n0), a, 0, 0, 0);
        #pragma unroll
        for (int jj = 0; jj < 4; ++jj) {
            const int m = nb + g * 4 + jj;
            if (m < N) {
                const size_t idx = (size_t)m * 64 + n0 * 16 + l15;
                h_out[idx] = h[idx] + (a[jj] + bn2_c[n0]);
            }
        }
    }
#undef LD_WN
}

extern "C" void kernel_launch(void* const* d_in, const int* in_sizes, int n_in,
                              void* d_out, int out_size, void* d_ws, size_t ws_size,
                              hipStream_t stream) {
    const float* h     = (const float*)d_in[0];
    const float* coord = (const float*)d_in[1];
    const int*   ei    = (const int*)  d_in[2];
    const float* ea    = (const float*)d_in[3];
    const float* We1   = (const float*)d_in[4];
    const float* be1   = (const float*)d_in[5];
    const float* We2   = (const float*)d_in[6];
    const float* be2   = (const float*)d_in[7];
    const float* Wn1   = (const float*)d_in[8];
    const float* bn1   = (const float*)d_in[9];
    const float* Wn2   = (const float*)d_in[10];
    const float* bn2   = (const float*)d_in[11];
    const float* Wc1   = (const float*)d_in[12];
    const float* bc1   = (const float*)d_in[13];
    const float* Wc2   = (const float*)d_in[14];

    const int N = in_sizes[0] / DD;     // h is [N,64]
    const int E = in_sizes[3] / 2;      // edge_attr is [E,2]

    float* out       = (float*)d_out;
    float* h_out     = out;
    float* coord_out = out + (size_t)N * DD;

    // workspace layout (16B aligned)
    char* base = (char*)d_ws;
    ushort_t* hbf   = (ushort_t*)base;                              // N*64*2 B
    const size_t o_wf    = (size_t)N * DD * 2;
    ushort_t* wf    = (ushort_t*)(base + o_wf);                     // 32768*2 B
    const size_t o_agg   = o_wf + 32768 * 2;
    ushort_t* aggbf = (ushort_t*)(base + o_agg);                    // N*64*2 B
    const size_t o_c4    = o_agg + (size_t)N * DD * 2;
    float4* coord4  = (float4*)(base + o_c4);                       // N*16 B
    const size_t o_cnt   = o_c4 + (size_t)N * 16;
    int* cnt_i      = (int*)(base + o_cnt);                         // N*4 B
    const size_t o_slots = o_cnt + (size_t)N * 4;
    int* slots      = (int*)(base + o_slots);                       // N*SLOTMAX*4 B
    const size_t o_tr    = o_slots + (size_t)N * SLOTMAX * 4;
    float4* trans4  = (float4*)(base + o_tr);                       // E*16 B
    const size_t o_ef    = o_tr + (size_t)E * 16;
    ushort_t* efbf  = (ushort_t*)(base + o_ef);                     // E*64*2 B

    hipMemsetAsync((void*)cnt_i, 0, (size_t)N * 4, stream);

    // combined prep: hist+slots | h->bf16 | coord4 | weight frags
    const int histBlocks = (E + 255) / 256;
    const int total8     = N * DD / 8;
    const int hbfBlocks  = (total8 + 255) / 256;
    const int c4Blocks   = (N + 255) / 256;
    const int wfBlocks   = (32768 + 255) / 256;
    prep_all<<<histBlocks + hbfBlocks + c4Blocks + wfBlocks, 256, 0, stream>>>(
        h, coord, We1, We2, Wc1, Wn1, Wn2, be1, be2, bc1, ei,
        hbf, wf, coord4, cnt_i, slots, N, E, total8,
        histBlocks, hbfBlocks, c4Blocks);

    // edge: edge-major tiles of 16 consecutive edges, persistent 1024x512
    const int ntiles = (E + 15) / 16;
    const int eblocks = 1024;
    const int totalWaves = eblocks * 8;
    egcl_edge<<<eblocks, 512, 0, stream>>>(
        hbf, wf, coord4, ei, ea, Wc2,
        (uint_t*)efbf, trans4, E, ntiles, totalWaves);

    // aggregation: one wave per node
    const int ablocks = (N + 3) / 4;
    egcl_agg<<<ablocks, 256, 0, stream>>>(
        efbf, trans4, slots, cnt_i, coord4, aggbf, coord_out, N);

    // node MLP: one wave per 16 nodes
    const int nwaves  = (N + 15) / 16;
    const int nblocks = (nwaves + 7) / 8;
    egcl_node<<<nblocks, 512, 0, stream>>>(
        hbf, aggbf, wf, h, bn1, bn2, h_out, N);
}